// Round 1
// baseline (586791.357 us; speedup 1.0000x reference)
//
#include <hip/hip_runtime.h>
#include <math.h>

#define NN    2048
#define DE    128
#define DH    256
#define NE    65536
#define NPAIR 1024
#define SWEEPS 8

// ---------------- Brent-Luk round-robin permutation (physical positions) -------------
__device__ __forceinline__ int bl_perm(int pos) {
  if (pos == 0) return 0;
  int k = pos >> 1;
  if ((pos & 1) == 0) return (k == NPAIR - 1) ? (NN - 1) : (pos + 2);
  return (k == 0) ? 2 : (pos - 2);
}

// rotation params for physical pair (2k, 2k+1), computed from the READ buffer (race-free)
__device__ __forceinline__ void jrot(const float* __restrict__ Ain, int k, float& c, float& s) {
  int p = 2 * k, q = p + 1;
  float app = Ain[((size_t)p << 11) + p];
  float aqq = Ain[((size_t)q << 11) + q];
  float apq = Ain[((size_t)p << 11) + q];
  if (fabsf(apq) <= 1e-30f) { c = 1.f; s = 0.f; return; }
  float tau = (aqq - app) / (2.f * apq);
  float den = fabsf(tau) + sqrtf(1.f + tau * tau);
  float t = ((tau >= 0.f) ? 1.f : -1.f) / den;
  c = 1.f / sqrtf(1.f + t * t);
  s = t * c;
}

// one Jacobi round: A' = P (J^T A J) P^T ; V' = V J P^T  (ping-pong buffers)
__global__ __launch_bounds__(256) void jacobi_update(
    const float* __restrict__ Ain, float* __restrict__ Aout,
    const float* __restrict__ Vin, float* __restrict__ Vout)
{
  int t = blockIdx.x * 256 + threadIdx.x;
  if (t < 1048576) {                    // A part: 1024x1024 2x2 blocks
    int ki = t >> 10, kj = t & 1023;
    float ci, si, cj, sj;
    jrot(Ain, ki, ci, si);
    jrot(Ain, kj, cj, sj);
    int r0 = ki << 1, c0 = kj << 1;
    const float2 top = *(const float2*)(Ain + ((size_t)r0 << 11) + c0);
    const float2 bot = *(const float2*)(Ain + ((size_t)(r0 + 1) << 11) + c0);
    float t00 = ci * top.x - si * bot.x, t01 = ci * top.y - si * bot.y;
    float t10 = si * top.x + ci * bot.x, t11 = si * top.y + ci * bot.y;
    float b00 = cj * t00 - sj * t01, b01 = sj * t00 + cj * t01;
    float b10 = cj * t10 - sj * t11, b11 = sj * t10 + cj * t11;
    int nr0 = bl_perm(r0), nr1 = bl_perm(r0 + 1);
    int nc0 = bl_perm(c0), nc1 = bl_perm(c0 + 1);
    Aout[((size_t)nr0 << 11) + nc0] = b00;
    Aout[((size_t)nr0 << 11) + nc1] = b01;
    Aout[((size_t)nr1 << 11) + nc0] = b10;
    Aout[((size_t)nr1 << 11) + nc1] = b11;
  } else {                              // V part: 2048 rows x 1024 pairs
    int v = t - 1048576;
    int i = v >> 10, k = v & 1023;
    float c, s;
    jrot(Ain, k, c, s);
    int c0 = k << 1;
    const float2 vv = *(const float2*)(Vin + ((size_t)i << 11) + c0);
    int nc0 = bl_perm(c0), nc1 = bl_perm(c0 + 1);
    Vout[((size_t)i << 11) + nc0] = c * vv.x - s * vv.y;
    Vout[((size_t)i << 11) + nc1] = s * vv.x + c * vv.y;
  }
}

// ---------------- graph / SAGE stage ----------------
__global__ void edge_deg_adj(const int* __restrict__ ei, const float* __restrict__ attr,
                             float* __restrict__ deg, float* __restrict__ Adense)
{
  int e = blockIdx.x * 256 + threadIdx.x;
  if (e >= NE) return;
  int s = ei[e], t = ei[NE + e];
  atomicAdd(&deg[t], 1.0f);
  Adense[((size_t)s << 11) + t] = attr[e];
}

__global__ void edge_agg(const int* __restrict__ ei, const float* __restrict__ attr,
                         const float* __restrict__ x, float* __restrict__ agg)
{
  int t0 = blockIdx.x * 256 + threadIdx.x;   // NE*32 items
  int e = t0 >> 5, c4 = (t0 & 31) * 4;
  int s = ei[e], t = ei[NE + e];
  float a = attr[e];
  const float4 xv = *(const float4*)(x + (size_t)s * DE + c4);
  atomicAdd(&agg[(size_t)t * DE + c4 + 0], xv.x * a);
  atomicAdd(&agg[(size_t)t * DE + c4 + 1], xv.y * a);
  atomicAdd(&agg[(size_t)t * DE + c4 + 2], xv.z * a);
  atomicAdd(&agg[(size_t)t * DE + c4 + 3], xv.w * a);
}

__global__ void div_agg(float* __restrict__ agg, const float* __restrict__ deg)
{
  int idx = blockIdx.x * 256 + threadIdx.x;  // NN*DE
  agg[idx] /= fmaxf(deg[idx >> 7], 1.0f);
}

__global__ __launch_bounds__(256) void gnn_h(const float* __restrict__ x, const float* __restrict__ agg,
        const float* __restrict__ wself, const float* __restrict__ wnbr,
        const float* __restrict__ bg, float* __restrict__ h)
{
  __shared__ float xs[16][DE];
  __shared__ float as[16][DE];
  int tx = threadIdx.x % 16, ty = threadIdx.x / 16;
  int i0 = blockIdx.y * 16, j = blockIdx.x * 16 + tx;
  for (int e = threadIdx.x; e < 16 * DE; e += 256) {
    int r = e >> 7, k = e & 127;
    xs[r][k] = x[(size_t)(i0 + r) * DE + k];
    as[r][k] = agg[(size_t)(i0 + r) * DE + k];
  }
  __syncthreads();
  float acc = bg[j];
  for (int k = 0; k < DE; ++k)
    acc += xs[ty][k] * wself[k * DH + j] + as[ty][k] * wnbr[k * DH + j];
  h[(size_t)(i0 + ty) * DH + j] = fmaxf(acc, 0.f);
}

__global__ void u_s_kernel(const float* __restrict__ h, const float* __restrict__ wlin,
                           float* __restrict__ u, float* __restrict__ srow)
{
  int i = blockIdx.x, j = threadIdx.x;      // 2048 blocks x 256
  float hv = h[(size_t)i * DH + j];
  float w = wlin[j];
  u[(size_t)i * DH + j] = hv * w;
  float p = hv * hv * w;
  for (int off = 32; off; off >>= 1) p += __shfl_down(p, off, 64);
  __shared__ float sw[4];
  if ((j & 63) == 0) sw[j >> 6] = p;
  __syncthreads();
  if (j == 0) srow[i] = sw[0] + sw[1] + sw[2] + sw[3];
}

// ---------------- generic 64x64x16 tiled fp32 GEMM ----------------
// C[M,N] = A'(m,k) * B'(k,n); TA: A'[m,k]=A[k*lda+m] else A[m*lda+k]; similarly TB.
// MODE 0: plain store.  MODE 1: logits = s[m]+s[n]+b[0]-2*acc
template<int TA, int TB, int MODE>
__global__ __launch_bounds__(256) void gemm64(int M, int Nn, int K,
            const float* __restrict__ A, int lda,
            const float* __restrict__ B, int ldb,
            float* __restrict__ Cc, int ldc,
            const float* __restrict__ svec, const float* __restrict__ bptr)
{
  __shared__ float As[16][65];
  __shared__ float Bs[16][65];
  const int tid = threadIdx.x;
  const int tx = tid % 16, ty = tid / 16;
  const int m0 = blockIdx.y * 64, n0 = blockIdx.x * 64;
  float acc[4][4] = {};
  for (int k0 = 0; k0 < K; k0 += 16) {
    if (TA == 0) {
      int mm = tid >> 2, kkb = (tid & 3) * 4;
      const float4 v = *(const float4*)(A + (size_t)(m0 + mm) * lda + k0 + kkb);
      As[kkb + 0][mm] = v.x; As[kkb + 1][mm] = v.y; As[kkb + 2][mm] = v.z; As[kkb + 3][mm] = v.w;
    } else {
      int kk = tid >> 4, mmb = (tid & 15) * 4;
      const float4 v = *(const float4*)(A + (size_t)(k0 + kk) * lda + m0 + mmb);
      As[kk][mmb + 0] = v.x; As[kk][mmb + 1] = v.y; As[kk][mmb + 2] = v.z; As[kk][mmb + 3] = v.w;
    }
    if (TB == 0) {
      int kk = tid >> 4, nnb = (tid & 15) * 4;
      const float4 v = *(const float4*)(B + (size_t)(k0 + kk) * ldb + n0 + nnb);
      Bs[kk][nnb + 0] = v.x; Bs[kk][nnb + 1] = v.y; Bs[kk][nnb + 2] = v.z; Bs[kk][nnb + 3] = v.w;
    } else {
      int nn = tid >> 2, kkb = (tid & 3) * 4;
      const float4 v = *(const float4*)(B + (size_t)(n0 + nn) * ldb + k0 + kkb);
      Bs[kkb + 0][nn] = v.x; Bs[kkb + 1][nn] = v.y; Bs[kkb + 2][nn] = v.z; Bs[kkb + 3][nn] = v.w;
    }
    __syncthreads();
    #pragma unroll
    for (int kk = 0; kk < 16; ++kk) {
      float a0 = As[kk][ty * 4 + 0], a1 = As[kk][ty * 4 + 1], a2 = As[kk][ty * 4 + 2], a3 = As[kk][ty * 4 + 3];
      float b0 = Bs[kk][tx * 4 + 0], b1 = Bs[kk][tx * 4 + 1], b2 = Bs[kk][tx * 4 + 2], b3 = Bs[kk][tx * 4 + 3];
      acc[0][0] += a0 * b0; acc[0][1] += a0 * b1; acc[0][2] += a0 * b2; acc[0][3] += a0 * b3;
      acc[1][0] += a1 * b0; acc[1][1] += a1 * b1; acc[1][2] += a1 * b2; acc[1][3] += a1 * b3;
      acc[2][0] += a2 * b0; acc[2][1] += a2 * b1; acc[2][2] += a2 * b2; acc[2][3] += a2 * b3;
      acc[3][0] += a3 * b0; acc[3][1] += a3 * b1; acc[3][2] += a3 * b2; acc[3][3] += a3 * b3;
    }
    __syncthreads();
  }
  #pragma unroll
  for (int r = 0; r < 4; ++r) {
    int m = m0 + ty * 4 + r;
    #pragma unroll
    for (int c = 0; c < 4; ++c) {
      int n = n0 + tx * 4 + c;
      float v = acc[r][c];
      if (MODE == 1) v = svec[m] + svec[n] + bptr[0] - 2.f * v;
      Cc[(size_t)m * ldc + n] = v;
    }
  }
}

// ---------------- loss ----------------
__global__ void loss_kernel(const float* __restrict__ logits, const float* __restrict__ gt,
                            double* __restrict__ acc)
{
  int base = blockIdx.x * 1024 + threadIdx.x;
  float local = 0.f;
  #pragma unroll
  for (int it = 0; it < 4; ++it) {
    int idx = base + it * 256;
    float l = logits[idx], g = gt[idx];
    float ls = (l > 0.f) ? -log1pf(expf(-l)) : (l - log1pf(expf(l)));   // log sigmoid(l)
    local += g * ls + (1.f - g) * (ls - l);                              // log sig(-l) = ls - l
  }
  double dl = (double)local;
  for (int off = 32; off; off >>= 1) dl += __shfl_down(dl, off, 64);
  __shared__ double sred[4];
  if ((threadIdx.x & 63) == 0) sred[threadIdx.x >> 6] = dl;
  __syncthreads();
  if (threadIdx.x == 0) atomicAdd(acc, sred[0] + sred[1] + sred[2] + sred[3]);
}

__global__ void loss_fin(const double* __restrict__ acc, float* __restrict__ out)
{
  out[0] = (float)(-acc[0] / (double)((size_t)NN * NN));
}

// ---------------- eigh prep / post ----------------
__global__ void init_av(const float* __restrict__ logits, float* __restrict__ A0v,
                        float* __restrict__ V0v, float* __restrict__ G)
{
  int idx = blockIdx.x * 256 + threadIdx.x;   // NN*NN
  float g = 1.f / (1.f + expf(-logits[idx]));
  A0v[idx] = g;
  G[idx] = g;
  int i = idx >> 11, j = idx & (NN - 1);
  V0v[idx] = (i == j) ? 1.f : 0.f;
}

__global__ void get_diag(const float* __restrict__ A, float* __restrict__ d)
{
  int p = blockIdx.x * 256 + threadIdx.x;
  if (p < NN) d[p] = A[((size_t)p << 11) + p];
}

__global__ __launch_bounds__(256) void rank_kernel(const float* __restrict__ d, int* __restrict__ rnk)
{
  __shared__ float sd[NN];
  for (int i = threadIdx.x; i < NN; i += 256) sd[i] = d[i];
  __syncthreads();
  int p = blockIdx.x * 256 + threadIdx.x;
  float dp = sd[p];
  int r = 0;
  for (int q = 0; q < NN; ++q) {
    float dq = sd[q];
    r += (dq < dp) || (dq == dp && q < p);
  }
  rnk[p] = r;
}

__global__ __launch_bounds__(256) void colsum_kernel(const float* __restrict__ V, float* __restrict__ colsum)
{
  int b = blockIdx.x;                       // 256 blocks x 8 rows
  for (int c = threadIdx.x; c < NN; c += 256) {
    float acc = 0.f;
    #pragma unroll
    for (int r = 0; r < 8; ++r) acc += V[((size_t)(b * 8 + r) << 11) + c];
    atomicAdd(&colsum[c], acc);
  }
}

__global__ __launch_bounds__(256) void build_c(const float* __restrict__ V, const float* __restrict__ colsum,
        const float* __restrict__ d, const int* __restrict__ rnk, float* __restrict__ C)
{
  int idx = blockIdx.x * 256 + threadIdx.x; // NN*NN
  int i = idx >> 11, p = idx & (NN - 1);
  float sf = sqrtf(fmaxf(d[p], 1e-6f));
  float sgn = (colsum[p] >= 0.f) ? 1.f : -1.f;
  float v = V[idx] * sgn * sf;
  v = (v > 0.1f) ? v : 0.f;
  C[((size_t)i << 11) + rnk[p]] = v;
}

__global__ void rownorm(float* __restrict__ C)
{
  int i = blockIdx.x;
  float s = 0.f;
  for (int c = threadIdx.x; c < NN; c += 256) s += C[((size_t)i << 11) + c];
  for (int off = 32; off; off >>= 1) s += __shfl_down(s, off, 64);
  __shared__ float sw[4];
  if ((threadIdx.x & 63) == 0) sw[threadIdx.x >> 6] = s;
  __syncthreads();
  __shared__ float stot;
  if (threadIdx.x == 0) { float t = sw[0] + sw[1] + sw[2] + sw[3]; stot = (t == 0.f) ? 1.f : t; }
  __syncthreads();
  for (int c = threadIdx.x; c < NN; c += 256) C[((size_t)i << 11) + c] /= stot;
}

// ---------------- driver ----------------
extern "C" void kernel_launch(void* const* d_in, const int* in_sizes, int n_in,
                              void* d_out, int out_size, void* d_ws, size_t ws_size,
                              hipStream_t stream)
{
  const float* x     = (const float*)d_in[0];
  const float* eattr = (const float*)d_in[1];
  const float* gtrue = (const float*)d_in[2];
  const float* wself = (const float*)d_in[3];
  const float* wnbr  = (const float*)d_in[4];
  const float* bgnn  = (const float*)d_in[5];
  const float* wlin  = (const float*)d_in[6];
  const float* blin  = (const float*)d_in[7];
  const int*   eidx  = (const int*)d_in[8];

  float* out       = (float*)d_out;
  float* o_xnew    = out;                 // 2048*256
  float* o_acoarse = out + 524288;        // 2048*2048 (holds dense A until the final GEMM)
  float* o_c       = out + 4718592;       // 2048*2048
  float* o_loss    = out + 8912896;       // 1
  float* o_g       = out + 8912897;       // 2048*2048

  float*  ws       = (float*)d_ws;
  float*  w_h      = ws;                  // 524288
  float*  w_u      = ws + 524288;         // 524288
  float*  w_agg    = ws + 1048576;        // 262144
  float*  w_deg    = ws + 1310720;        // 2048
  float*  w_srow   = ws + 1312768;        // 2048
  float*  w_logits = ws + 1314816;        // 4194304
  float*  w_a0     = ws + 5509120;        // 4194304
  float*  w_a1     = ws + 9703424;        // 4194304
  float*  w_v0     = ws + 13897728;       // 4194304
  float*  w_v1     = ws + 18092032;       // 4194304
  float*  w_d      = ws + 22286336;       // 2048
  int*    w_rank   = (int*)(ws + 22288384);  // 2048
  float*  w_colsum = ws + 22290432;       // 2048
  double* w_lacc   = (double*)(ws + 22292480); // 8-byte aligned

  // zero accumulation targets (ws/out are poisoned 0xAA by the harness)
  hipMemsetAsync(w_agg, 0, (262144 + 2048) * sizeof(float), stream);                 // agg + deg
  hipMemsetAsync(w_colsum, 0, 2048 * sizeof(float) + sizeof(double), stream);        // colsum + lossAcc
  hipMemsetAsync(o_acoarse, 0, (size_t)NN * NN * sizeof(float), stream);             // dense A staging

  edge_deg_adj<<<NE / 256, 256, 0, stream>>>(eidx, eattr, w_deg, o_acoarse);
  edge_agg<<<(NE * 32) / 256, 256, 0, stream>>>(eidx, eattr, x, w_agg);
  div_agg<<<(NN * DE) / 256, 256, 0, stream>>>(w_agg, w_deg);
  gnn_h<<<dim3(DH / 16, NN / 16), 256, 0, stream>>>(x, w_agg, wself, wnbr, bgnn, w_h);
  u_s_kernel<<<NN, 256, 0, stream>>>(w_h, wlin, w_u, w_srow);

  // logits = s_i + s_j + b - 2 * u h^T  (NT gemm)
  gemm64<0, 1, 1><<<dim3(32, 32), 256, 0, stream>>>(NN, NN, DH, w_u, DH, w_h, DH,
                                                    w_logits, NN, w_srow, blin);
  loss_kernel<<<(NN * NN) / 1024, 256, 0, stream>>>(w_logits, gtrue, w_lacc);
  loss_fin<<<1, 1, 0, stream>>>(w_lacc, o_loss);

  init_av<<<(NN * NN) / 256, 256, 0, stream>>>(w_logits, w_a0, w_v0, o_g);

  // ------- Jacobi eigendecomposition: SWEEPS sweeps of (N-1) Brent-Luk rounds -------
  float* Aa = w_a0; float* Ab = w_a1; float* Va = w_v0; float* Vb = w_v1;
  const int R = (NN - 1) * SWEEPS;
  for (int r = 0; r < R; ++r) {
    jacobi_update<<<12288, 256, 0, stream>>>(Aa, Ab, Va, Vb);
    float* tp;
    tp = Aa; Aa = Ab; Ab = tp;
    tp = Va; Va = Vb; Vb = tp;
  }

  get_diag<<<NN / 256, 256, 0, stream>>>(Aa, w_d);
  rank_kernel<<<NN / 256, 256, 0, stream>>>(w_d, w_rank);
  colsum_kernel<<<NN / 8, 256, 0, stream>>>(Va, w_colsum);
  build_c<<<(NN * NN) / 256, 256, 0, stream>>>(Va, w_colsum, w_d, w_rank, o_c);
  rownorm<<<NN, 256, 0, stream>>>(o_c);

  // x_new = C^T h
  gemm64<1, 0, 0><<<dim3(DH / 64, NN / 64), 256, 0, stream>>>(NN, DH, NN, o_c, NN, w_h, DH,
                                                              o_xnew, DH, nullptr, nullptr);
  // T = C^T A  (reuse the non-final Jacobi A buffer)
  float* Tbuf = Ab;
  gemm64<1, 0, 0><<<dim3(32, 32), 256, 0, stream>>>(NN, NN, NN, o_c, NN, o_acoarse, NN,
                                                    Tbuf, NN, nullptr, nullptr);
  // A_coarse = T C  (overwrites the dense-A staging region with the final output)
  gemm64<0, 0, 0><<<dim3(32, 32), 256, 0, stream>>>(NN, NN, NN, Tbuf, NN, o_c, NN,
                                                    o_acoarse, NN, nullptr, nullptr);
}

// Round 2
// 343021.411 us; speedup vs baseline: 1.7107x; 1.7107x over previous
//
#include <hip/hip_runtime.h>
#include <math.h>

#define NN    2048
#define DE    128
#define DH    256
#define NE    65536
#define NPAIR 1024
#define SWEEPS 8

// ---------------- Brent-Luk round-robin permutation (physical positions) -------------
__device__ __forceinline__ int bl_perm(int pos) {
  if (pos == 0) return 0;
  int k = pos >> 1;
  if ((pos & 1) == 0) return (k == NPAIR - 1) ? (NN - 1) : (pos + 2);
  return (k == 0) ? 2 : (pos - 2);
}

// rotation params for physical pair (2k, 2k+1), computed from the READ buffer (race-free)
__device__ __forceinline__ void jrot(const float* __restrict__ Ain, int k, float& c, float& s) {
  int p = 2 * k, q = p + 1;
  float app = Ain[((size_t)p << 11) + p];
  float aqq = Ain[((size_t)q << 11) + q];
  float apq = Ain[((size_t)p << 11) + q];
  if (fabsf(apq) <= 1e-30f) { c = 1.f; s = 0.f; return; }
  float tau = (aqq - app) / (2.f * apq);
  float den = fabsf(tau) + sqrtf(1.f + tau * tau);
  float t = ((tau >= 0.f) ? 1.f : -1.f) / den;
  c = 1.f / sqrtf(1.f + t * t);
  s = t * c;
}

// one Jacobi round: A' = P (J^T A J) P^T ; V' = V J P^T  (ping-pong buffers)
// v2: rotations computed once per block into LDS (kills ~9M scattered diag
// loads/round that made v1 3.3x over the BW floor). Update math identical to v1.
__global__ __launch_bounds__(256) void jacobi_update2(
    const float* __restrict__ Ain, float* __restrict__ Aout,
    const float* __restrict__ Vin, float* __restrict__ Vout)
{
  __shared__ float2 rI[16];
  __shared__ float2 rJ[16];
  const int tid = threadIdx.x;
  const int b = blockIdx.x;
  const int ty = tid >> 4, tx = tid & 15;

  if (b < 4096) {                      // A part: 64x64 blocks of 16x16 pair-tiles
    const int tki0 = (b >> 6) << 4, tkj0 = (b & 63) << 4;
    if (tid < 16) {
      float c, s; jrot(Ain, tki0 + tid, c, s); rI[tid] = make_float2(c, s);
    } else if (tid < 32) {
      float c, s; jrot(Ain, tkj0 + tid - 16, c, s); rJ[tid - 16] = make_float2(c, s);
    }
    __syncthreads();
    const int ki = tki0 + ty, kj = tkj0 + tx;
    const float ci = rI[ty].x, si = rI[ty].y;
    const float cj = rJ[tx].x, sj = rJ[tx].y;
    const int r0 = ki << 1, c0 = kj << 1;
    const float2 top = *(const float2*)(Ain + ((size_t)r0 << 11) + c0);
    const float2 bot = *(const float2*)(Ain + ((size_t)(r0 + 1) << 11) + c0);
    float t00 = ci * top.x - si * bot.x, t01 = ci * top.y - si * bot.y;
    float t10 = si * top.x + ci * bot.x, t11 = si * top.y + ci * bot.y;
    float b00 = cj * t00 - sj * t01, b01 = sj * t00 + cj * t01;
    float b10 = cj * t10 - sj * t11, b11 = sj * t10 + cj * t11;
    int nr0 = bl_perm(r0), nr1 = bl_perm(r0 + 1);
    int nc0 = bl_perm(c0), nc1 = bl_perm(c0 + 1);
    Aout[((size_t)nr0 << 11) + nc0] = b00;
    Aout[((size_t)nr0 << 11) + nc1] = b01;
    Aout[((size_t)nr1 << 11) + nc0] = b10;
    Aout[((size_t)nr1 << 11) + nc1] = b11;
  } else {                             // V part: 128x64 blocks of (16 rows x 16 pairs)
    const int vb = b - 4096;
    const int ri0 = (vb >> 6) << 4, pk0 = (vb & 63) << 4;
    if (tid < 16) {
      float c, s; jrot(Ain, pk0 + tid, c, s); rJ[tid] = make_float2(c, s);
    }
    __syncthreads();
    const int i = ri0 + ty, k = pk0 + tx;
    const float c = rJ[tx].x, s = rJ[tx].y;
    const int c0 = k << 1;
    const float2 vv = *(const float2*)(Vin + ((size_t)i << 11) + c0);
    int nc0 = bl_perm(c0), nc1 = bl_perm(c0 + 1);
    Vout[((size_t)i << 11) + nc0] = c * vv.x - s * vv.y;
    Vout[((size_t)i << 11) + nc1] = s * vv.x + c * vv.y;
  }
}

// ---------------- graph / SAGE stage ----------------
__global__ void edge_deg_adj(const int* __restrict__ ei, const float* __restrict__ attr,
                             float* __restrict__ deg, float* __restrict__ Adense)
{
  int e = blockIdx.x * 256 + threadIdx.x;
  if (e >= NE) return;
  int s = ei[e], t = ei[NE + e];
  atomicAdd(&deg[t], 1.0f);
  Adense[((size_t)s << 11) + t] = attr[e];
}

__global__ void edge_agg(const int* __restrict__ ei, const float* __restrict__ attr,
                         const float* __restrict__ x, float* __restrict__ agg)
{
  int t0 = blockIdx.x * 256 + threadIdx.x;   // NE*32 items
  int e = t0 >> 5, c4 = (t0 & 31) * 4;
  int s = ei[e], t = ei[NE + e];
  float a = attr[e];
  const float4 xv = *(const float4*)(x + (size_t)s * DE + c4);
  atomicAdd(&agg[(size_t)t * DE + c4 + 0], xv.x * a);
  atomicAdd(&agg[(size_t)t * DE + c4 + 1], xv.y * a);
  atomicAdd(&agg[(size_t)t * DE + c4 + 2], xv.z * a);
  atomicAdd(&agg[(size_t)t * DE + c4 + 3], xv.w * a);
}

__global__ void div_agg(float* __restrict__ agg, const float* __restrict__ deg)
{
  int idx = blockIdx.x * 256 + threadIdx.x;  // NN*DE
  agg[idx] /= fmaxf(deg[idx >> 7], 1.0f);
}

__global__ __launch_bounds__(256) void gnn_h(const float* __restrict__ x, const float* __restrict__ agg,
        const float* __restrict__ wself, const float* __restrict__ wnbr,
        const float* __restrict__ bg, float* __restrict__ h)
{
  __shared__ float xs[16][DE];
  __shared__ float as[16][DE];
  int tx = threadIdx.x % 16, ty = threadIdx.x / 16;
  int i0 = blockIdx.y * 16, j = blockIdx.x * 16 + tx;
  for (int e = threadIdx.x; e < 16 * DE; e += 256) {
    int r = e >> 7, k = e & 127;
    xs[r][k] = x[(size_t)(i0 + r) * DE + k];
    as[r][k] = agg[(size_t)(i0 + r) * DE + k];
  }
  __syncthreads();
  float acc = bg[j];
  for (int k = 0; k < DE; ++k)
    acc += xs[ty][k] * wself[k * DH + j] + as[ty][k] * wnbr[k * DH + j];
  h[(size_t)(i0 + ty) * DH + j] = fmaxf(acc, 0.f);
}

__global__ void u_s_kernel(const float* __restrict__ h, const float* __restrict__ wlin,
                           float* __restrict__ u, float* __restrict__ srow)
{
  int i = blockIdx.x, j = threadIdx.x;      // 2048 blocks x 256
  float hv = h[(size_t)i * DH + j];
  float w = wlin[j];
  u[(size_t)i * DH + j] = hv * w;
  float p = hv * hv * w;
  for (int off = 32; off; off >>= 1) p += __shfl_down(p, off, 64);
  __shared__ float sw[4];
  if ((j & 63) == 0) sw[j >> 6] = p;
  __syncthreads();
  if (j == 0) srow[i] = sw[0] + sw[1] + sw[2] + sw[3];
}

// ---------------- generic 64x64x16 tiled fp32 GEMM ----------------
template<int TA, int TB, int MODE>
__global__ __launch_bounds__(256) void gemm64(int M, int Nn, int K,
            const float* __restrict__ A, int lda,
            const float* __restrict__ B, int ldb,
            float* __restrict__ Cc, int ldc,
            const float* __restrict__ svec, const float* __restrict__ bptr)
{
  __shared__ float As[16][65];
  __shared__ float Bs[16][65];
  const int tid = threadIdx.x;
  const int tx = tid % 16, ty = tid / 16;
  const int m0 = blockIdx.y * 64, n0 = blockIdx.x * 64;
  float acc[4][4] = {};
  for (int k0 = 0; k0 < K; k0 += 16) {
    if (TA == 0) {
      int mm = tid >> 2, kkb = (tid & 3) * 4;
      const float4 v = *(const float4*)(A + (size_t)(m0 + mm) * lda + k0 + kkb);
      As[kkb + 0][mm] = v.x; As[kkb + 1][mm] = v.y; As[kkb + 2][mm] = v.z; As[kkb + 3][mm] = v.w;
    } else {
      int kk = tid >> 4, mmb = (tid & 15) * 4;
      const float4 v = *(const float4*)(A + (size_t)(k0 + kk) * lda + m0 + mmb);
      As[kk][mmb + 0] = v.x; As[kk][mmb + 1] = v.y; As[kk][mmb + 2] = v.z; As[kk][mmb + 3] = v.w;
    }
    if (TB == 0) {
      int kk = tid >> 4, nnb = (tid & 15) * 4;
      const float4 v = *(const float4*)(B + (size_t)(k0 + kk) * ldb + n0 + nnb);
      Bs[kk][nnb + 0] = v.x; Bs[kk][nnb + 1] = v.y; Bs[kk][nnb + 2] = v.z; Bs[kk][nnb + 3] = v.w;
    } else {
      int nn = tid >> 2, kkb = (tid & 3) * 4;
      const float4 v = *(const float4*)(B + (size_t)(n0 + nn) * ldb + k0 + kkb);
      Bs[kkb + 0][nn] = v.x; Bs[kkb + 1][nn] = v.y; Bs[kkb + 2][nn] = v.z; Bs[kkb + 3][nn] = v.w;
    }
    __syncthreads();
    #pragma unroll
    for (int kk = 0; kk < 16; ++kk) {
      float a0 = As[kk][ty * 4 + 0], a1 = As[kk][ty * 4 + 1], a2 = As[kk][ty * 4 + 2], a3 = As[kk][ty * 4 + 3];
      float b0 = Bs[kk][tx * 4 + 0], b1 = Bs[kk][tx * 4 + 1], b2 = Bs[kk][tx * 4 + 2], b3 = Bs[kk][tx * 4 + 3];
      acc[0][0] += a0 * b0; acc[0][1] += a0 * b1; acc[0][2] += a0 * b2; acc[0][3] += a0 * b3;
      acc[1][0] += a1 * b0; acc[1][1] += a1 * b1; acc[1][2] += a1 * b2; acc[1][3] += a1 * b3;
      acc[2][0] += a2 * b0; acc[2][1] += a2 * b1; acc[2][2] += a2 * b2; acc[2][3] += a2 * b3;
      acc[3][0] += a3 * b0; acc[3][1] += a3 * b1; acc[3][2] += a3 * b2; acc[3][3] += a3 * b3;
    }
    __syncthreads();
  }
  #pragma unroll
  for (int r = 0; r < 4; ++r) {
    int m = m0 + ty * 4 + r;
    #pragma unroll
    for (int c = 0; c < 4; ++c) {
      int n = n0 + tx * 4 + c;
      float v = acc[r][c];
      if (MODE == 1) v = svec[m] + svec[n] + bptr[0] - 2.f * v;
      Cc[(size_t)m * ldc + n] = v;
    }
  }
}

// ---------------- loss ----------------
__global__ void loss_kernel(const float* __restrict__ logits, const float* __restrict__ gt,
                            double* __restrict__ acc)
{
  int base = blockIdx.x * 1024 + threadIdx.x;
  float local = 0.f;
  #pragma unroll
  for (int it = 0; it < 4; ++it) {
    int idx = base + it * 256;
    float l = logits[idx], g = gt[idx];
    float ls = (l > 0.f) ? -log1pf(expf(-l)) : (l - log1pf(expf(l)));   // log sigmoid(l)
    local += g * ls + (1.f - g) * (ls - l);
  }
  double dl = (double)local;
  for (int off = 32; off; off >>= 1) dl += __shfl_down(dl, off, 64);
  __shared__ double sred[4];
  if ((threadIdx.x & 63) == 0) sred[threadIdx.x >> 6] = dl;
  __syncthreads();
  if (threadIdx.x == 0) atomicAdd(acc, sred[0] + sred[1] + sred[2] + sred[3]);
}

__global__ void loss_fin(const double* __restrict__ acc, float* __restrict__ out)
{
  out[0] = (float)(-acc[0] / (double)((size_t)NN * NN));
}

// ---------------- eigh prep / post ----------------
__global__ void init_av(const float* __restrict__ logits, float* __restrict__ A0v,
                        float* __restrict__ V0v, float* __restrict__ G)
{
  int idx = blockIdx.x * 256 + threadIdx.x;   // NN*NN
  float g = 1.f / (1.f + expf(-logits[idx]));
  A0v[idx] = g;
  G[idx] = g;
  int i = idx >> 11, j = idx & (NN - 1);
  V0v[idx] = (i == j) ? 1.f : 0.f;
}

__global__ void get_diag(const float* __restrict__ A, float* __restrict__ d)
{
  int p = blockIdx.x * 256 + threadIdx.x;
  if (p < NN) d[p] = A[((size_t)p << 11) + p];
}

__global__ __launch_bounds__(256) void rank_kernel(const float* __restrict__ d, int* __restrict__ rnk)
{
  __shared__ float sd[NN];
  for (int i = threadIdx.x; i < NN; i += 256) sd[i] = d[i];
  __syncthreads();
  int p = blockIdx.x * 256 + threadIdx.x;
  float dp = sd[p];
  int r = 0;
  for (int q = 0; q < NN; ++q) {
    float dq = sd[q];
    r += (dq < dp) || (dq == dp && q < p);
  }
  rnk[p] = r;
}

__global__ __launch_bounds__(256) void colsum_kernel(const float* __restrict__ V, float* __restrict__ colsum)
{
  int b = blockIdx.x;                       // 256 blocks x 8 rows
  for (int c = threadIdx.x; c < NN; c += 256) {
    float acc = 0.f;
    #pragma unroll
    for (int r = 0; r < 8; ++r) acc += V[((size_t)(b * 8 + r) << 11) + c];
    atomicAdd(&colsum[c], acc);
  }
}

__global__ __launch_bounds__(256) void build_c(const float* __restrict__ V, const float* __restrict__ colsum,
        const float* __restrict__ d, const int* __restrict__ rnk, float* __restrict__ C)
{
  int idx = blockIdx.x * 256 + threadIdx.x; // NN*NN
  int i = idx >> 11, p = idx & (NN - 1);
  float sf = sqrtf(fmaxf(d[p], 1e-6f));
  float sgn = (colsum[p] >= 0.f) ? 1.f : -1.f;
  float v = V[idx] * sgn * sf;
  v = (v > 0.1f) ? v : 0.f;
  C[((size_t)i << 11) + rnk[p]] = v;
}

__global__ void rownorm(float* __restrict__ C)
{
  int i = blockIdx.x;
  float s = 0.f;
  for (int c = threadIdx.x; c < NN; c += 256) s += C[((size_t)i << 11) + c];
  for (int off = 32; off; off >>= 1) s += __shfl_down(s, off, 64);
  __shared__ float sw[4];
  if ((threadIdx.x & 63) == 0) sw[threadIdx.x >> 6] = s;
  __syncthreads();
  __shared__ float stot;
  if (threadIdx.x == 0) { float t = sw[0] + sw[1] + sw[2] + sw[3]; stot = (t == 0.f) ? 1.f : t; }
  __syncthreads();
  for (int c = threadIdx.x; c < NN; c += 256) C[((size_t)i << 11) + c] /= stot;
}

// ---------------- driver ----------------
extern "C" void kernel_launch(void* const* d_in, const int* in_sizes, int n_in,
                              void* d_out, int out_size, void* d_ws, size_t ws_size,
                              hipStream_t stream)
{
  const float* x     = (const float*)d_in[0];
  const float* eattr = (const float*)d_in[1];
  const float* gtrue = (const float*)d_in[2];
  const float* wself = (const float*)d_in[3];
  const float* wnbr  = (const float*)d_in[4];
  const float* bgnn  = (const float*)d_in[5];
  const float* wlin  = (const float*)d_in[6];
  const float* blin  = (const float*)d_in[7];
  const int*   eidx  = (const int*)d_in[8];

  float* out       = (float*)d_out;
  float* o_xnew    = out;                 // 2048*256
  float* o_acoarse = out + 524288;        // 2048*2048 (holds dense A until the final GEMM)
  float* o_c       = out + 4718592;       // 2048*2048
  float* o_loss    = out + 8912896;       // 1
  float* o_g       = out + 8912897;       // 2048*2048

  float*  ws       = (float*)d_ws;
  float*  w_h      = ws;                  // 524288
  float*  w_u      = ws + 524288;         // 524288
  float*  w_agg    = ws + 1048576;        // 262144
  float*  w_deg    = ws + 1310720;        // 2048
  float*  w_srow   = ws + 1312768;        // 2048
  float*  w_logits = ws + 1314816;        // 4194304
  float*  w_a0     = ws + 5509120;        // 4194304
  float*  w_a1     = ws + 9703424;        // 4194304
  float*  w_v0     = ws + 13897728;       // 4194304
  float*  w_v1     = ws + 18092032;       // 4194304
  float*  w_d      = ws + 22286336;       // 2048
  int*    w_rank   = (int*)(ws + 22288384);  // 2048
  float*  w_colsum = ws + 22290432;       // 2048
  double* w_lacc   = (double*)(ws + 22292480); // 8-byte aligned

  hipMemsetAsync(w_agg, 0, (262144 + 2048) * sizeof(float), stream);
  hipMemsetAsync(w_colsum, 0, 2048 * sizeof(float) + sizeof(double), stream);
  hipMemsetAsync(o_acoarse, 0, (size_t)NN * NN * sizeof(float), stream);

  edge_deg_adj<<<NE / 256, 256, 0, stream>>>(eidx, eattr, w_deg, o_acoarse);
  edge_agg<<<(NE * 32) / 256, 256, 0, stream>>>(eidx, eattr, x, w_agg);
  div_agg<<<(NN * DE) / 256, 256, 0, stream>>>(w_agg, w_deg);
  gnn_h<<<dim3(DH / 16, NN / 16), 256, 0, stream>>>(x, w_agg, wself, wnbr, bgnn, w_h);
  u_s_kernel<<<NN, 256, 0, stream>>>(w_h, wlin, w_u, w_srow);

  gemm64<0, 1, 1><<<dim3(32, 32), 256, 0, stream>>>(NN, NN, DH, w_u, DH, w_h, DH,
                                                    w_logits, NN, w_srow, blin);
  loss_kernel<<<(NN * NN) / 1024, 256, 0, stream>>>(w_logits, gtrue, w_lacc);
  loss_fin<<<1, 1, 0, stream>>>(w_lacc, o_loss);

  init_av<<<(NN * NN) / 256, 256, 0, stream>>>(w_logits, w_a0, w_v0, o_g);

  // ------- Jacobi eigendecomposition: SWEEPS sweeps of (N-1) Brent-Luk rounds -------
  float* Aa = w_a0; float* Ab = w_a1; float* Va = w_v0; float* Vb = w_v1;
  const int R = (NN - 1) * SWEEPS;
  for (int r = 0; r < R; ++r) {
    jacobi_update2<<<12288, 256, 0, stream>>>(Aa, Ab, Va, Vb);
    float* tp;
    tp = Aa; Aa = Ab; Ab = tp;
    tp = Va; Va = Vb; Vb = tp;
  }

  get_diag<<<NN / 256, 256, 0, stream>>>(Aa, w_d);
  rank_kernel<<<NN / 256, 256, 0, stream>>>(w_d, w_rank);
  colsum_kernel<<<NN / 8, 256, 0, stream>>>(Va, w_colsum);
  build_c<<<(NN * NN) / 256, 256, 0, stream>>>(Va, w_colsum, w_d, w_rank, o_c);
  rownorm<<<NN, 256, 0, stream>>>(o_c);

  gemm64<1, 0, 0><<<dim3(DH / 64, NN / 64), 256, 0, stream>>>(NN, DH, NN, o_c, NN, w_h, DH,
                                                              o_xnew, DH, nullptr, nullptr);
  float* Tbuf = Ab;
  gemm64<1, 0, 0><<<dim3(32, 32), 256, 0, stream>>>(NN, NN, NN, o_c, NN, o_acoarse, NN,
                                                    Tbuf, NN, nullptr, nullptr);
  gemm64<0, 0, 0><<<dim3(32, 32), 256, 0, stream>>>(NN, NN, NN, Tbuf, NN, o_c, NN,
                                                    o_acoarse, NN, nullptr, nullptr);
}

// Round 3
// 200134.229 us; speedup vs baseline: 2.9320x; 1.7140x over previous
//
#include <hip/hip_runtime.h>
#include <math.h>

#define NN    2048
#define DE    128
#define DH    256
#define NE    65536
#define NBLK  128      // outer blocks of 16 rows
#define BS    16
#define OUTER_SWEEPS 9
#define LSW   6        // local Jacobi sweeps in the 32x32 solve

// rotation params — identical formula to the passing scalar version
__device__ __forceinline__ void jrot2(float app, float aqq, float apq, float& c, float& s) {
  if (fabsf(apq) <= 1e-30f) { c = 1.f; s = 0.f; return; }
  float tau = (aqq - app) / (2.f * apq);
  float den = fabsf(tau) + sqrtf(1.f + tau * tau);
  float t = ((tau >= 0.f) ? 1.f : -1.f) / den;
  c = 1.f / sqrtf(1.f + t * t);
  s = t * c;
}

// round-robin (circle method) pairing of 128 blocks; round rr in [0,127)
__device__ __forceinline__ void pair_of(int rr, int i, int& bp, int& bq) {
  int p, q;
  if (i == 0) { p = NBLK - 1; q = rr % (NBLK - 1); }
  else { p = (rr + i) % (NBLK - 1); q = (rr - i + (NBLK - 1)) % (NBLK - 1); }
  bp = min(p, q); bq = max(p, q);
}

// ---------- block solve: diagonalize 32x32 [App Apq; Aqp Aqq] in LDS, emit U ----------
__global__ __launch_bounds__(256) void block_solve(const float* __restrict__ A,
                                                   float* __restrict__ Ublk, int rr)
{
  __shared__ float S[32][33];
  __shared__ float U[32][33];
  __shared__ float rc[16], rs[16];
  __shared__ int pa[16], pb[16];
  const int tid = threadIdx.x;
  int bp, bq; pair_of(rr, blockIdx.x, bp, bq);
  {
    int a = tid >> 3, c4 = (tid & 7) * 4;
    int gr = (a < BS) ? (bp * BS + a) : (bq * BS + a - BS);
    int gc = (c4 < BS) ? (bp * BS + c4) : (bq * BS + c4 - BS);
    const float4 v = *(const float4*)(A + ((size_t)gr << 11) + gc);
    S[a][c4] = v.x; S[a][c4 + 1] = v.y; S[a][c4 + 2] = v.z; S[a][c4 + 3] = v.w;
    U[a][c4]     = (a == c4)     ? 1.f : 0.f;
    U[a][c4 + 1] = (a == c4 + 1) ? 1.f : 0.f;
    U[a][c4 + 2] = (a == c4 + 2) ? 1.f : 0.f;
    U[a][c4 + 3] = (a == c4 + 3) ? 1.f : 0.f;
  }
  __syncthreads();
  for (int sw = 0; sw < LSW; ++sw) {
    for (int r2 = 0; r2 < 31; ++r2) {
      if (tid < 16) {
        int aa, bb;
        if (tid == 0) { aa = 31; bb = r2; }
        else { aa = (r2 + tid) % 31; bb = (r2 - tid + 31) % 31; }
        int pp = min(aa, bb), qq = max(aa, bb);
        pa[tid] = pp; pb[tid] = qq;
        float c, s; jrot2(S[pp][pp], S[qq][qq], S[pp][qq], c, s);
        rc[tid] = c; rs[tid] = s;
      }
      __syncthreads();
      {  // row update: 16 pairs x 32 cols, disjoint tasks
        int k = tid >> 5, col = tid & 31;
        #pragma unroll
        for (int it = 0; it < 2; ++it, k += 8) {
          float c = rc[k], s = rs[k];
          int P = pa[k], Q = pb[k];
          float xp = S[P][col], xq = S[Q][col];
          S[P][col] = c * xp - s * xq;
          S[Q][col] = s * xp + c * xq;
        }
      }
      __syncthreads();
      {  // col update on S and U: 16 pairs x 32 rows x {S,U}
        #pragma unroll
        for (int it = 0; it < 4; ++it) {
          int t = tid + it * 256;
          int k = (t >> 5) & 15, row = t & 31;
          float c = rc[k], s = rs[k];
          int P = pa[k], Q = pb[k];
          if (t < 512) {
            float xp = S[row][P], xq = S[row][Q];
            S[row][P] = c * xp - s * xq;
            S[row][Q] = s * xp + c * xq;
          } else {
            float xp = U[row][P], xq = U[row][Q];
            U[row][P] = c * xp - s * xq;
            U[row][Q] = s * xp + c * xq;
          }
        }
      }
      __syncthreads();
    }
  }
  {
    int a = tid >> 3, c4 = (tid & 7) * 4;
    *(float4*)(Ublk + ((size_t)blockIdx.x << 10) + (a << 5) + c4) =
        make_float4(U[a][c4], U[a][c4 + 1], U[a][c4 + 2], U[a][c4 + 3]);
  }
}

// ---------- block apply: A[Si,Sj] = Ui^T A[Si,Sj] Uj (in place), V[:,Sj] = V[:,Sj] Uj ----------
// blocks [0,4096): A tiles (i=b>>6, j=b&63); [4096,8192): V tiles (j=vb>>6, rowtile=vb&63)
__global__ __launch_bounds__(64) void block_apply(float* __restrict__ A, float* __restrict__ V,
                                                  const float* __restrict__ Ublk, int rr)
{
  __shared__ float SA[32][36];
  __shared__ float U1[32][36];
  __shared__ float U2[32][36];
  __shared__ float T[32][33];
  const int tid = threadIdx.x;
  const int ta = tid >> 3, tb = tid & 7;          // 8x8 threads, 4x4 regs each
  const int b = blockIdx.x;

  if (b < 4096) {
    const int i = b >> 6, j = b & 63;
    int bpi, bqi; pair_of(rr, i, bpi, bqi);
    int bpj, bqj; pair_of(rr, j, bpj, bqj);
    #pragma unroll
    for (int it = 0; it < 4; ++it) {
      int t = tid + it * 64;
      int a = t >> 3, c4 = (t & 7) * 4;
      *(float4*)&U1[a][c4] = *(const float4*)(Ublk + ((size_t)i << 10) + (a << 5) + c4);
      *(float4*)&U2[a][c4] = *(const float4*)(Ublk + ((size_t)j << 10) + (a << 5) + c4);
      int gr = (a < BS) ? (bpi * BS + a) : (bqi * BS + a - BS);
      int gc = (c4 < BS) ? (bpj * BS + c4) : (bqj * BS + c4 - BS);
      *(float4*)&SA[a][c4] = *(const float4*)(A + ((size_t)gr << 11) + gc);
    }
    __syncthreads();
    // stage 1: T = U_i^T * SA
    float acc[4][4] = {};
    for (int k = 0; k < 32; ++k) {
      const float4 u = *(const float4*)&U1[k][ta << 2];
      const float4 x = *(const float4*)&SA[k][tb << 2];
      acc[0][0] += u.x * x.x; acc[0][1] += u.x * x.y; acc[0][2] += u.x * x.z; acc[0][3] += u.x * x.w;
      acc[1][0] += u.y * x.x; acc[1][1] += u.y * x.y; acc[1][2] += u.y * x.z; acc[1][3] += u.y * x.w;
      acc[2][0] += u.z * x.x; acc[2][1] += u.z * x.y; acc[2][2] += u.z * x.z; acc[2][3] += u.z * x.w;
      acc[3][0] += u.w * x.x; acc[3][1] += u.w * x.y; acc[3][2] += u.w * x.z; acc[3][3] += u.w * x.w;
    }
    #pragma unroll
    for (int r = 0; r < 4; ++r)
      #pragma unroll
      for (int c = 0; c < 4; ++c)
        T[(ta << 2) + r][(tb << 2) + c] = acc[r][c];
    __syncthreads();
    // stage 2: Out = T * U_j
    float o[4][4] = {};
    for (int k = 0; k < 32; ++k) {
      const float4 u = *(const float4*)&U2[k][tb << 2];
      #pragma unroll
      for (int r = 0; r < 4; ++r) {
        float tv = T[(ta << 2) + r][k];
        o[r][0] += tv * u.x; o[r][1] += tv * u.y; o[r][2] += tv * u.z; o[r][3] += tv * u.w;
      }
    }
    #pragma unroll
    for (int r = 0; r < 4; ++r) {
      int a = (ta << 2) + r;
      int gr = (a < BS) ? (bpi * BS + a) : (bqi * BS + a - BS);
      int c4 = tb << 2;
      int gc = (c4 < BS) ? (bpj * BS + c4) : (bqj * BS + c4 - BS);
      *(float4*)(A + ((size_t)gr << 11) + gc) = make_float4(o[r][0], o[r][1], o[r][2], o[r][3]);
    }
  } else {
    const int vb = b - 4096;
    const int j = vb >> 6, rt = vb & 63;
    int bpj, bqj; pair_of(rr, j, bpj, bqj);
    #pragma unroll
    for (int it = 0; it < 4; ++it) {
      int t = tid + it * 64;
      int a = t >> 3, c4 = (t & 7) * 4;
      *(float4*)&U2[a][c4] = *(const float4*)(Ublk + ((size_t)j << 10) + (a << 5) + c4);
      int gc = (c4 < BS) ? (bpj * BS + c4) : (bqj * BS + c4 - BS);
      const float4 vv = *(const float4*)(V + ((size_t)(rt * 32 + a) << 11) + gc);
      T[a][c4] = vv.x; T[a][c4 + 1] = vv.y; T[a][c4 + 2] = vv.z; T[a][c4 + 3] = vv.w;
    }
    __syncthreads();
    float o[4][4] = {};
    for (int k = 0; k < 32; ++k) {
      const float4 u = *(const float4*)&U2[k][tb << 2];
      #pragma unroll
      for (int r = 0; r < 4; ++r) {
        float tv = T[(ta << 2) + r][k];
        o[r][0] += tv * u.x; o[r][1] += tv * u.y; o[r][2] += tv * u.z; o[r][3] += tv * u.w;
      }
    }
    #pragma unroll
    for (int r = 0; r < 4; ++r) {
      int c4 = tb << 2;
      int gc = (c4 < BS) ? (bpj * BS + c4) : (bqj * BS + c4 - BS);
      *(float4*)(V + ((size_t)(rt * 32 + (ta << 2) + r) << 11) + gc) =
          make_float4(o[r][0], o[r][1], o[r][2], o[r][3]);
    }
  }
}

// ---------------- graph / SAGE stage ----------------
__global__ void edge_deg_adj(const int* __restrict__ ei, const float* __restrict__ attr,
                             float* __restrict__ deg, float* __restrict__ Adense)
{
  int e = blockIdx.x * 256 + threadIdx.x;
  if (e >= NE) return;
  int s = ei[e], t = ei[NE + e];
  atomicAdd(&deg[t], 1.0f);
  Adense[((size_t)s << 11) + t] = attr[e];
}

__global__ void edge_agg(const int* __restrict__ ei, const float* __restrict__ attr,
                         const float* __restrict__ x, float* __restrict__ agg)
{
  int t0 = blockIdx.x * 256 + threadIdx.x;   // NE*32 items
  int e = t0 >> 5, c4 = (t0 & 31) * 4;
  int s = ei[e], t = ei[NE + e];
  float a = attr[e];
  const float4 xv = *(const float4*)(x + (size_t)s * DE + c4);
  atomicAdd(&agg[(size_t)t * DE + c4 + 0], xv.x * a);
  atomicAdd(&agg[(size_t)t * DE + c4 + 1], xv.y * a);
  atomicAdd(&agg[(size_t)t * DE + c4 + 2], xv.z * a);
  atomicAdd(&agg[(size_t)t * DE + c4 + 3], xv.w * a);
}

__global__ void div_agg(float* __restrict__ agg, const float* __restrict__ deg)
{
  int idx = blockIdx.x * 256 + threadIdx.x;  // NN*DE
  agg[idx] /= fmaxf(deg[idx >> 7], 1.0f);
}

__global__ __launch_bounds__(256) void gnn_h(const float* __restrict__ x, const float* __restrict__ agg,
        const float* __restrict__ wself, const float* __restrict__ wnbr,
        const float* __restrict__ bg, float* __restrict__ h)
{
  __shared__ float xs[16][DE];
  __shared__ float as[16][DE];
  int tx = threadIdx.x % 16, ty = threadIdx.x / 16;
  int i0 = blockIdx.y * 16, j = blockIdx.x * 16 + tx;
  for (int e = threadIdx.x; e < 16 * DE; e += 256) {
    int r = e >> 7, k = e & 127;
    xs[r][k] = x[(size_t)(i0 + r) * DE + k];
    as[r][k] = agg[(size_t)(i0 + r) * DE + k];
  }
  __syncthreads();
  float acc = bg[j];
  for (int k = 0; k < DE; ++k)
    acc += xs[ty][k] * wself[k * DH + j] + as[ty][k] * wnbr[k * DH + j];
  h[(size_t)(i0 + ty) * DH + j] = fmaxf(acc, 0.f);
}

__global__ void u_s_kernel(const float* __restrict__ h, const float* __restrict__ wlin,
                           float* __restrict__ u, float* __restrict__ srow)
{
  int i = blockIdx.x, j = threadIdx.x;      // 2048 blocks x 256
  float hv = h[(size_t)i * DH + j];
  float w = wlin[j];
  u[(size_t)i * DH + j] = hv * w;
  float p = hv * hv * w;
  for (int off = 32; off; off >>= 1) p += __shfl_down(p, off, 64);
  __shared__ float sw[4];
  if ((j & 63) == 0) sw[j >> 6] = p;
  __syncthreads();
  if (j == 0) srow[i] = sw[0] + sw[1] + sw[2] + sw[3];
}

// ---------------- generic 64x64x16 tiled fp32 GEMM ----------------
template<int TA, int TB, int MODE>
__global__ __launch_bounds__(256) void gemm64(int M, int Nn, int K,
            const float* __restrict__ A, int lda,
            const float* __restrict__ B, int ldb,
            float* __restrict__ Cc, int ldc,
            const float* __restrict__ svec, const float* __restrict__ bptr)
{
  __shared__ float As[16][65];
  __shared__ float Bs[16][65];
  const int tid = threadIdx.x;
  const int tx = tid % 16, ty = tid / 16;
  const int m0 = blockIdx.y * 64, n0 = blockIdx.x * 64;
  float acc[4][4] = {};
  for (int k0 = 0; k0 < K; k0 += 16) {
    if (TA == 0) {
      int mm = tid >> 2, kkb = (tid & 3) * 4;
      const float4 v = *(const float4*)(A + (size_t)(m0 + mm) * lda + k0 + kkb);
      As[kkb + 0][mm] = v.x; As[kkb + 1][mm] = v.y; As[kkb + 2][mm] = v.z; As[kkb + 3][mm] = v.w;
    } else {
      int kk = tid >> 4, mmb = (tid & 15) * 4;
      const float4 v = *(const float4*)(A + (size_t)(k0 + kk) * lda + m0 + mmb);
      As[kk][mmb + 0] = v.x; As[kk][mmb + 1] = v.y; As[kk][mmb + 2] = v.z; As[kk][mmb + 3] = v.w;
    }
    if (TB == 0) {
      int kk = tid >> 4, nnb = (tid & 15) * 4;
      const float4 v = *(const float4*)(B + (size_t)(k0 + kk) * ldb + n0 + nnb);
      Bs[kk][nnb + 0] = v.x; Bs[kk][nnb + 1] = v.y; Bs[kk][nnb + 2] = v.z; Bs[kk][nnb + 3] = v.w;
    } else {
      int nn = tid >> 2, kkb = (tid & 3) * 4;
      const float4 v = *(const float4*)(B + (size_t)(n0 + nn) * ldb + k0 + kkb);
      Bs[kkb + 0][nn] = v.x; Bs[kkb + 1][nn] = v.y; Bs[kkb + 2][nn] = v.z; Bs[kkb + 3][nn] = v.w;
    }
    __syncthreads();
    #pragma unroll
    for (int kk = 0; kk < 16; ++kk) {
      float a0 = As[kk][ty * 4 + 0], a1 = As[kk][ty * 4 + 1], a2 = As[kk][ty * 4 + 2], a3 = As[kk][ty * 4 + 3];
      float b0 = Bs[kk][tx * 4 + 0], b1 = Bs[kk][tx * 4 + 1], b2 = Bs[kk][tx * 4 + 2], b3 = Bs[kk][tx * 4 + 3];
      acc[0][0] += a0 * b0; acc[0][1] += a0 * b1; acc[0][2] += a0 * b2; acc[0][3] += a0 * b3;
      acc[1][0] += a1 * b0; acc[1][1] += a1 * b1; acc[1][2] += a1 * b2; acc[1][3] += a1 * b3;
      acc[2][0] += a2 * b0; acc[2][1] += a2 * b1; acc[2][2] += a2 * b2; acc[2][3] += a2 * b3;
      acc[3][0] += a3 * b0; acc[3][1] += a3 * b1; acc[3][2] += a3 * b2; acc[3][3] += a3 * b3;
    }
    __syncthreads();
  }
  #pragma unroll
  for (int r = 0; r < 4; ++r) {
    int m = m0 + ty * 4 + r;
    #pragma unroll
    for (int c = 0; c < 4; ++c) {
      int n = n0 + tx * 4 + c;
      float v = acc[r][c];
      if (MODE == 1) v = svec[m] + svec[n] + bptr[0] - 2.f * v;
      Cc[(size_t)m * ldc + n] = v;
    }
  }
}

// ---------------- loss ----------------
__global__ void loss_kernel(const float* __restrict__ logits, const float* __restrict__ gt,
                            double* __restrict__ acc)
{
  int base = blockIdx.x * 1024 + threadIdx.x;
  float local = 0.f;
  #pragma unroll
  for (int it = 0; it < 4; ++it) {
    int idx = base + it * 256;
    float l = logits[idx], g = gt[idx];
    float ls = (l > 0.f) ? -log1pf(expf(-l)) : (l - log1pf(expf(l)));   // log sigmoid(l)
    local += g * ls + (1.f - g) * (ls - l);
  }
  double dl = (double)local;
  for (int off = 32; off; off >>= 1) dl += __shfl_down(dl, off, 64);
  __shared__ double sred[4];
  if ((threadIdx.x & 63) == 0) sred[threadIdx.x >> 6] = dl;
  __syncthreads();
  if (threadIdx.x == 0) atomicAdd(acc, sred[0] + sred[1] + sred[2] + sred[3]);
}

__global__ void loss_fin(const double* __restrict__ acc, float* __restrict__ out)
{
  out[0] = (float)(-acc[0] / (double)((size_t)NN * NN));
}

// ---------------- eigh prep / post ----------------
__global__ void init_av(const float* __restrict__ logits, float* __restrict__ A0v,
                        float* __restrict__ V0v, float* __restrict__ G)
{
  int idx = blockIdx.x * 256 + threadIdx.x;   // NN*NN
  float g = 1.f / (1.f + expf(-logits[idx]));
  A0v[idx] = g;
  G[idx] = g;
  int i = idx >> 11, j = idx & (NN - 1);
  V0v[idx] = (i == j) ? 1.f : 0.f;
}

__global__ void get_diag(const float* __restrict__ A, float* __restrict__ d)
{
  int p = blockIdx.x * 256 + threadIdx.x;
  if (p < NN) d[p] = A[((size_t)p << 11) + p];
}

__global__ __launch_bounds__(256) void rank_kernel(const float* __restrict__ d, int* __restrict__ rnk)
{
  __shared__ float sd[NN];
  for (int i = threadIdx.x; i < NN; i += 256) sd[i] = d[i];
  __syncthreads();
  int p = blockIdx.x * 256 + threadIdx.x;
  float dp = sd[p];
  int r = 0;
  for (int q = 0; q < NN; ++q) {
    float dq = sd[q];
    r += (dq < dp) || (dq == dp && q < p);
  }
  rnk[p] = r;
}

__global__ __launch_bounds__(256) void colsum_kernel(const float* __restrict__ V, float* __restrict__ colsum)
{
  int b = blockIdx.x;                       // 256 blocks x 8 rows
  for (int c = threadIdx.x; c < NN; c += 256) {
    float acc = 0.f;
    #pragma unroll
    for (int r = 0; r < 8; ++r) acc += V[((size_t)(b * 8 + r) << 11) + c];
    atomicAdd(&colsum[c], acc);
  }
}

__global__ __launch_bounds__(256) void build_c(const float* __restrict__ V, const float* __restrict__ colsum,
        const float* __restrict__ d, const int* __restrict__ rnk, float* __restrict__ C)
{
  int idx = blockIdx.x * 256 + threadIdx.x; // NN*NN
  int i = idx >> 11, p = idx & (NN - 1);
  float sf = sqrtf(fmaxf(d[p], 1e-6f));
  float sgn = (colsum[p] >= 0.f) ? 1.f : -1.f;
  float v = V[idx] * sgn * sf;
  v = (v > 0.1f) ? v : 0.f;
  C[((size_t)i << 11) + rnk[p]] = v;
}

__global__ void rownorm(float* __restrict__ C)
{
  int i = blockIdx.x;
  float s = 0.f;
  for (int c = threadIdx.x; c < NN; c += 256) s += C[((size_t)i << 11) + c];
  for (int off = 32; off; off >>= 1) s += __shfl_down(s, off, 64);
  __shared__ float sw[4];
  if ((threadIdx.x & 63) == 0) sw[threadIdx.x >> 6] = s;
  __syncthreads();
  __shared__ float stot;
  if (threadIdx.x == 0) { float t = sw[0] + sw[1] + sw[2] + sw[3]; stot = (t == 0.f) ? 1.f : t; }
  __syncthreads();
  for (int c = threadIdx.x; c < NN; c += 256) C[((size_t)i << 11) + c] /= stot;
}

// ---------------- driver ----------------
extern "C" void kernel_launch(void* const* d_in, const int* in_sizes, int n_in,
                              void* d_out, int out_size, void* d_ws, size_t ws_size,
                              hipStream_t stream)
{
  const float* x     = (const float*)d_in[0];
  const float* eattr = (const float*)d_in[1];
  const float* gtrue = (const float*)d_in[2];
  const float* wself = (const float*)d_in[3];
  const float* wnbr  = (const float*)d_in[4];
  const float* bgnn  = (const float*)d_in[5];
  const float* wlin  = (const float*)d_in[6];
  const float* blin  = (const float*)d_in[7];
  const int*   eidx  = (const int*)d_in[8];

  float* out       = (float*)d_out;
  float* o_xnew    = out;                 // 2048*256
  float* o_acoarse = out + 524288;        // 2048*2048 (holds dense A until the final GEMM)
  float* o_c       = out + 4718592;       // 2048*2048
  float* o_loss    = out + 8912896;       // 1
  float* o_g       = out + 8912897;       // 2048*2048

  float*  ws       = (float*)d_ws;
  float*  w_h      = ws;                  // 524288
  float*  w_u      = ws + 524288;         // 524288
  float*  w_agg    = ws + 1048576;        // 262144
  float*  w_deg    = ws + 1310720;        // 2048
  float*  w_srow   = ws + 1312768;        // 2048
  float*  w_logits = ws + 1314816;        // 4194304
  float*  w_a0     = ws + 5509120;        // 4194304  (A, updated in place)
  float*  w_a1     = ws + 9703424;        // 4194304  (free; reused as Tbuf)
  float*  w_v0     = ws + 13897728;       // 4194304  (V, updated in place)
  float*  w_ublk   = ws + 18092032;       // 65536 (64 pairs x 32x32 U blocks)
  float*  w_d      = ws + 22286336;       // 2048
  int*    w_rank   = (int*)(ws + 22288384);  // 2048
  float*  w_colsum = ws + 22290432;       // 2048
  double* w_lacc   = (double*)(ws + 22292480); // 8-byte aligned

  hipMemsetAsync(w_agg, 0, (262144 + 2048) * sizeof(float), stream);
  hipMemsetAsync(w_colsum, 0, 2048 * sizeof(float) + sizeof(double), stream);
  hipMemsetAsync(o_acoarse, 0, (size_t)NN * NN * sizeof(float), stream);

  edge_deg_adj<<<NE / 256, 256, 0, stream>>>(eidx, eattr, w_deg, o_acoarse);
  edge_agg<<<(NE * 32) / 256, 256, 0, stream>>>(eidx, eattr, x, w_agg);
  div_agg<<<(NN * DE) / 256, 256, 0, stream>>>(w_agg, w_deg);
  gnn_h<<<dim3(DH / 16, NN / 16), 256, 0, stream>>>(x, w_agg, wself, wnbr, bgnn, w_h);
  u_s_kernel<<<NN, 256, 0, stream>>>(w_h, wlin, w_u, w_srow);

  gemm64<0, 1, 1><<<dim3(32, 32), 256, 0, stream>>>(NN, NN, DH, w_u, DH, w_h, DH,
                                                    w_logits, NN, w_srow, blin);
  loss_kernel<<<(NN * NN) / 1024, 256, 0, stream>>>(w_logits, gtrue, w_lacc);
  loss_fin<<<1, 1, 0, stream>>>(w_lacc, o_loss);

  init_av<<<(NN * NN) / 256, 256, 0, stream>>>(w_logits, w_a0, w_v0, o_g);

  // ------- block-Jacobi eigendecomposition: OUTER_SWEEPS x 127 rounds -------
  const int ROUNDS = (NBLK - 1) * OUTER_SWEEPS;
  for (int r = 0; r < ROUNDS; ++r) {
    int rr = r % (NBLK - 1);
    block_solve<<<NBLK / 2, 256, 0, stream>>>(w_a0, w_ublk, rr);
    block_apply<<<8192, 64, 0, stream>>>(w_a0, w_v0, w_ublk, rr);
  }

  get_diag<<<NN / 256, 256, 0, stream>>>(w_a0, w_d);
  rank_kernel<<<NN / 256, 256, 0, stream>>>(w_d, w_rank);
  colsum_kernel<<<NN / 8, 256, 0, stream>>>(w_v0, w_colsum);
  build_c<<<(NN * NN) / 256, 256, 0, stream>>>(w_v0, w_colsum, w_d, w_rank, o_c);
  rownorm<<<NN, 256, 0, stream>>>(o_c);

  gemm64<1, 0, 0><<<dim3(DH / 64, NN / 64), 256, 0, stream>>>(NN, DH, NN, o_c, NN, w_h, DH,
                                                              o_xnew, DH, nullptr, nullptr);
  float* Tbuf = w_a1;
  gemm64<1, 0, 0><<<dim3(32, 32), 256, 0, stream>>>(NN, NN, NN, o_c, NN, o_acoarse, NN,
                                                    Tbuf, NN, nullptr, nullptr);
  gemm64<0, 0, 0><<<dim3(32, 32), 256, 0, stream>>>(NN, NN, NN, Tbuf, NN, o_c, NN,
                                                    o_acoarse, NN, nullptr, nullptr);
}